// Round 1
// baseline (386.096 us; speedup 1.0000x reference)
//
#include <hip/hip_runtime.h>
#include <hip/hip_bf16.h>

#define DF 128

// flagI: 1 = edge_index stored as int64, 0 = int32
// flagD: 1 = x/W/b/out are bf16, 0 = fp32   (round-5 evidence: fp32 on this bench)

typedef __attribute__((ext_vector_type(8))) short shortx8;   // MFMA A/B frag (8 bf16)
typedef __attribute__((ext_vector_type(4))) float floatx4;   // MFMA C/D frag

__device__ __forceinline__ unsigned short f32_to_bf16_rne(float f) {
    unsigned int u = __float_as_uint(f);
    unsigned int r = (u >> 16) & 1u;
    u += 0x7FFFu + r;
    return (unsigned short)(u >> 16);
}
__device__ __forceinline__ float bf16_lo(unsigned int w) { return __uint_as_float(w << 16); }
__device__ __forceinline__ float bf16_hi(unsigned int w) { return __uint_as_float(w & 0xffff0000u); }
__device__ __forceinline__ unsigned int pack_bf16(float x, float y) {
    return ((unsigned int)f32_to_bf16_rne(y) << 16) | (unsigned int)f32_to_bf16_rne(x);
}

// ---------------- dtype detection ----------------
__global__ void detect_flags_kernel(const unsigned int* __restrict__ ew, int enwords,
                                    const unsigned short* __restrict__ xh, int xnh,
                                    int* __restrict__ flagI, int* __restrict__ flagD) {
    __shared__ int eodd_nz;
    __shared__ int xbig;
    if (threadIdx.x == 0) { eodd_nz = 0; xbig = 0; }
    __syncthreads();
    int f1 = 0;
    for (int i = 1 + 2 * (int)threadIdx.x; i < enwords; i += 2 * (int)blockDim.x)
        if (ew[i] != 0u) f1 = 1;
    int c = 0;
    for (int i = 2 * (int)threadIdx.x; i < xnh; i += 2 * (int)blockDim.x) {
        unsigned int e = ((unsigned int)xh[i] >> 7) & 0xFFu;
        if (e >= 0xC0u) c++;   // |v| >= 2^65 viewed as bf16 -> impossible for real data
    }
    if (f1) eodd_nz = 1;
    if (c) atomicAdd(&xbig, c);
    __syncthreads();
    if (threadIdx.x == 0) {
        *flagI = (eodd_nz == 0) ? 1 : 0;
        *flagD = (xbig > 8) ? 0 : 1;
    }
}

// ---------------- degree count (in-degree of dst), XCD-bucketed ----------------
// blockIdx&7 selects a dst-range bucket; with round-robin block->XCD dispatch all
// atomics to a given cnt cache line originate from ONE XCD -> no cross-XCD line
// ping-pong. The 64 blocks of a bucket collectively grid-stride the edge list.
__global__ __launch_bounds__(256) void count_deg_kernel(const int* __restrict__ eidx,
                                                        const int* __restrict__ flagI,
                                                        int E, int n, int* __restrict__ cnt) {
    int bucket = (int)(blockIdx.x & 7);
    int bsize = (n + 7) >> 3;
    int lo = bucket * bsize;
    int hi = lo + bsize; if (hi > n) hi = n;
    int nthr = (int)(gridDim.x >> 3) * (int)blockDim.x;
    int t0 = (int)(blockIdx.x >> 3) * (int)blockDim.x + (int)threadIdx.x;
    int isI64 = *flagI;
    const long long* p64 = (const long long*)eidx;
    for (int e = t0; e < E; e += nthr) {
        int d = isI64 ? (int)p64[(long long)E + e] : eidx[E + e];
        if (d < lo || d >= hi) continue;   // also rejects d<0 and d>=n
        int s = isI64 ? (int)p64[e] : eidx[e];
        if (s < 0 || s >= n) continue;     // must match scatter's filter
        atomicAdd(&cnt[d], 1);
    }
}

__global__ void dinv_kernel(const int* __restrict__ cnt, float* __restrict__ dinv, int n) {
    int i = blockIdx.x * blockDim.x + threadIdx.x;
    if (i < n) dinv[i] = rsqrtf((float)(cnt[i] + 1));
}

// ---------------- exclusive scan of cnt -> row_start ----------------
__global__ void scan_blocks_kernel(const int* __restrict__ cnt, int* __restrict__ row_start,
                                   int* __restrict__ partials, int n) {
    __shared__ int s[256];
    int i = blockIdx.x * 256 + threadIdx.x;
    int v = (i < n) ? cnt[i] : 0;
    s[threadIdx.x] = v;
    __syncthreads();
    for (int off = 1; off < 256; off <<= 1) {
        int t = ((int)threadIdx.x >= off) ? s[threadIdx.x - off] : 0;
        __syncthreads();
        s[threadIdx.x] += t;
        __syncthreads();
    }
    if (i < n) row_start[i] = s[threadIdx.x] - v;
    if (threadIdx.x == 255) partials[blockIdx.x] = s[255];
}

__global__ void scan_partials_kernel(int* __restrict__ partials, int nparts) {
    __shared__ int s[512];
    int v = ((int)threadIdx.x < nparts) ? partials[threadIdx.x] : 0;
    s[threadIdx.x] = v;
    __syncthreads();
    for (int off = 1; off < 512; off <<= 1) {
        int t = ((int)threadIdx.x >= off) ? s[threadIdx.x - off] : 0;
        __syncthreads();
        s[threadIdx.x] += t;
        __syncthreads();
    }
    if ((int)threadIdx.x < nparts) partials[threadIdx.x] = s[threadIdx.x] - v;
}

__global__ void finalize_rows_kernel(int* __restrict__ row_start, const int* __restrict__ partials,
                                     const int* __restrict__ cnt, int* __restrict__ cursor, int n) {
    int i = blockIdx.x * 256 + threadIdx.x;
    if (i < n) {
        int r = row_start[i] + partials[blockIdx.x];
        row_start[i] = r;
        cursor[i] = r;
        if (i == n - 1) row_start[n] = r + cnt[i];
    }
}

// ---------------- CSR scatter: pack {src, dinv[src]} per edge, XCD-bucketed ----------------
// Same bucketing as count_deg: each XCD owns a contiguous dst range, hence a
// contiguous ~E/8 slice of csr. All 8B scatter-stores to a 64B csr line come
// from one XCD's L2 -> line assembled in L2, single writeback (was ~8.4x
// write amplification: 54MB written for a 6.4MB buffer).
__global__ __launch_bounds__(256) void scatter_kernel(const int* __restrict__ eidx,
                                                      const int* __restrict__ flagI,
                                                      int E, int n, const float* __restrict__ dinv,
                                                      int* __restrict__ cursor, int2* __restrict__ csr) {
    int bucket = (int)(blockIdx.x & 7);
    int bsize = (n + 7) >> 3;
    int lo = bucket * bsize;
    int hi = lo + bsize; if (hi > n) hi = n;
    int nthr = (int)(gridDim.x >> 3) * (int)blockDim.x;
    int t0 = (int)(blockIdx.x >> 3) * (int)blockDim.x + (int)threadIdx.x;
    int isI64 = *flagI;
    const long long* p64 = (const long long*)eidx;
    for (int e = t0; e < E; e += nthr) {
        int d = isI64 ? (int)p64[(long long)E + e] : eidx[E + e];
        if (d < lo || d >= hi) continue;
        int s = isI64 ? (int)p64[e] : eidx[e];
        if (s < 0 || s >= n) continue;
        int pos = atomicAdd(&cursor[d], 1);
        int2 pk;
        pk.x = s;
        pk.y = __float_as_int(dinv[s]);
        csr[pos] = pk;
    }
}

// ---------------- cast x -> packed bf16 rows (or copy if already bf16) ----------------
__global__ void cast_x_kernel(const void* __restrict__ x, uint2* __restrict__ xb,
                              const int* __restrict__ flagD, int nw2) {
    int i = blockIdx.x * blockDim.x + threadIdx.x;
    if (i >= nw2) return;
    if (*flagD) {
        xb[i] = ((const uint2*)x)[i];
    } else {
        float4 v = ((const float4*)x)[i];
        uint2 o;
        o.x = pack_bf16(v.x, v.y);
        o.y = pack_bf16(v.z, v.w);
        xb[i] = o;
    }
}

// ---------------- cast W -> bf16 (once), b -> fp32 (once) ----------------
__global__ void cast_wb_kernel(const void* __restrict__ W, const void* __restrict__ b,
                               unsigned short* __restrict__ Wb, float* __restrict__ bias_f,
                               const int* __restrict__ flagD) {
    int i = blockIdx.x * 256 + threadIdx.x;
    int bf = *flagD;
    if (i < 128 * 128)
        Wb[i] = bf ? ((const unsigned short*)W)[i] : f32_to_bf16_rne(((const float*)W)[i]);
    if (i < 128)
        bias_f[i] = bf ? bf16_lo((unsigned int)((const unsigned short*)b)[i]) : ((const float*)b)[i];
}

// ---------------- hop: one wave per node, quarter-wave uint4 gathers ----------------
// lane = 16*e + c (e: edge slot 0..3, c: 16B chunk 0..15). Each iteration gathers
// 4 edge-rows with ONE dwordx4 per lane; fp32 accumulate 8 cols/lane; shfl-xor
// reduce across quarters; quarter 0 stores the 256B row.
// out[i] = di*(di*self + sum_s dinv[s]*h[s])
__global__ __launch_bounds__(256) void hop_kernel(const uint4* __restrict__ hin,
                                                  uint4* __restrict__ hout,
                                                  const int2* __restrict__ csr,
                                                  const int* __restrict__ row_start,
                                                  const float* __restrict__ dinv, int n) {
    int gw = (int)((blockIdx.x * 256 + threadIdx.x) >> 6);
    int lane = (int)(threadIdx.x & 63);
    if (gw >= n) return;
    int e = lane >> 4, c = lane & 15;
    float di = dinv[gw];
    int beg = row_start[gw], end = row_start[gw + 1];
    uint4 sv = hin[(size_t)gw * 16 + c];     // self row (broadcast across quarters)
    float a0 = 0.f, a1 = 0.f, a2 = 0.f, a3 = 0.f, a4 = 0.f, a5 = 0.f, a6 = 0.f, a7 = 0.f;
    for (int j = beg + e; j < end; j += 4) {
        int2 ed = csr[j];
        float w = __int_as_float(ed.y);
        uint4 v = hin[(size_t)ed.x * 16 + c];
        a0 += w * bf16_lo(v.x); a1 += w * bf16_hi(v.x);
        a2 += w * bf16_lo(v.y); a3 += w * bf16_hi(v.y);
        a4 += w * bf16_lo(v.z); a5 += w * bf16_hi(v.z);
        a6 += w * bf16_lo(v.w); a7 += w * bf16_hi(v.w);
    }
    // reduce the 4 quarter-partials for each column set
    a0 += __shfl_xor(a0, 16); a0 += __shfl_xor(a0, 32);
    a1 += __shfl_xor(a1, 16); a1 += __shfl_xor(a1, 32);
    a2 += __shfl_xor(a2, 16); a2 += __shfl_xor(a2, 32);
    a3 += __shfl_xor(a3, 16); a3 += __shfl_xor(a3, 32);
    a4 += __shfl_xor(a4, 16); a4 += __shfl_xor(a4, 32);
    a5 += __shfl_xor(a5, 16); a5 += __shfl_xor(a5, 32);
    a6 += __shfl_xor(a6, 16); a6 += __shfl_xor(a6, 32);
    a7 += __shfl_xor(a7, 16); a7 += __shfl_xor(a7, 32);
    // add self term and final scale
    a0 = di * (a0 + di * bf16_lo(sv.x)); a1 = di * (a1 + di * bf16_hi(sv.x));
    a2 = di * (a2 + di * bf16_lo(sv.y)); a3 = di * (a3 + di * bf16_hi(sv.y));
    a4 = di * (a4 + di * bf16_lo(sv.z)); a5 = di * (a5 + di * bf16_hi(sv.z));
    a6 = di * (a6 + di * bf16_lo(sv.w)); a7 = di * (a7 + di * bf16_hi(sv.w));
    if (e == 0) {
        uint4 o;
        o.x = pack_bf16(a0, a1);
        o.y = pack_bf16(a2, a3);
        o.z = pack_bf16(a4, a5);
        o.w = pack_bf16(a6, a7);
        hout[(size_t)gw * 16 + c] = o;
    }
}

// ---------------- MFMA linear: out = h @ Wb^T + bias (h,Wb bf16; out per flagD) ----------------
// 16x16x32 bf16 MFMA. A: lane holds A[m=lane&15][k=q*8+j], q=lane>>4.
// B: lane holds B[k=q*8+j][o=lane&15]. C/D: col=lane&15, row=q*4+reg.
// Grid-stride over 16-row strips so W-frag setup is amortized.
__global__ __launch_bounds__(256, 2) void linear_mfma_kernel(
        const unsigned short* __restrict__ h, const unsigned short* __restrict__ Wb,
        const float* __restrict__ bias_f, void* __restrict__ out,
        const int* __restrict__ flagD, int n) {
    int bf = *flagD;
    int wave = (int)(threadIdx.x >> 6);
    int lane = (int)(threadIdx.x & 63);
    int q = lane >> 4, m16 = lane & 15;

    shortx8 bfrag[8][4];
    float bias[8];
#pragma unroll
    for (int nt = 0; nt < 8; ++nt) {
        int wr = nt * 16 + m16;               // W row = output feature o
#pragma unroll
        for (int t = 0; t < 4; ++t)
            bfrag[nt][t] = *(const shortx8*)&Wb[wr * 128 + t * 32 + q * 8];
        bias[nt] = bias_f[wr];
    }

    int nstrips = (n + 15) / 16;
    int wid = (int)blockIdx.x * 4 + wave;
    int nw = (int)gridDim.x * 4;
    for (int s = wid; s < nstrips; s += nw) {
        int row0 = s * 16;
        int arow = row0 + m16;
        if (arow >= n) arow = n - 1;          // clamp (dup rows; stores guarded)
        shortx8 afrag[4];
#pragma unroll
        for (int t = 0; t < 4; ++t)
            afrag[t] = *(const shortx8*)&h[(size_t)arow * 128 + t * 32 + q * 8];

        floatx4 acc[8];
#pragma unroll
        for (int nt = 0; nt < 8; ++nt) acc[nt] = (floatx4){0.f, 0.f, 0.f, 0.f};
#pragma unroll
        for (int t = 0; t < 4; ++t)
#pragma unroll
            for (int nt = 0; nt < 8; ++nt)
                acc[nt] = __builtin_amdgcn_mfma_f32_16x16x32_bf16(afrag[t], bfrag[nt][t], acc[nt], 0, 0, 0);

#pragma unroll
        for (int nt = 0; nt < 8; ++nt)
#pragma unroll
            for (int r = 0; r < 4; ++r) {
                int row = row0 + q * 4 + r;
                if (row < n) {
                    float v = acc[nt][r] + bias[nt];
                    size_t oi = (size_t)row * 128 + nt * 16 + m16;
                    if (bf) ((unsigned short*)out)[oi] = f32_to_bf16_rne(v);
                    else    ((float*)out)[oi] = v;
                }
            }
    }
}

extern "C" void kernel_launch(void* const* d_in, const int* in_sizes, int n_in,
                              void* d_out, int out_size, void* d_ws, size_t ws_size,
                              hipStream_t stream) {
    const void* x = d_in[0];
    const int* eidx = (const int*)d_in[1];
    const void* W = d_in[2];
    const void* b = d_in[3];

    int n = in_sizes[0] / DF;   // 100000
    int E = in_sizes[1] / 2;    // 800000

    // workspace carve-up (~34 MB; d_out hosts the second bf16 ping buffer,
    // safe because out_size*2B >= 25.6MB even for bf16 output)
    char* ws = (char*)d_ws;
    size_t off = 0;
    auto alloc = [&](size_t bytes) -> void* {
        void* p = ws + off;
        off = (off + bytes + 255) & ~(size_t)255;
        return p;
    };
    unsigned int* hb = (unsigned int*)alloc((size_t)n * 64 * 4);   // bf16 rows, 25.6MB
    float* dinv      = (float*)alloc((size_t)n * 4);
    int*   cnt       = (int*)alloc((size_t)n * 4);
    int*   row_start = (int*)alloc((size_t)(n + 1) * 4);
    int*   cursor    = (int*)alloc((size_t)n * 4);
    int*   partials  = (int*)alloc(4096);
    int*   flagI     = (int*)alloc(256);
    int*   flagD     = (int*)alloc(256);
    unsigned short* Wb = (unsigned short*)alloc(128 * 128 * 2);    // bf16 W
    float* bias_f    = (float*)alloc(128 * 4);
    int2*  csr       = (int2*)alloc((size_t)E * 8);                // {src, dinv[src]}
    unsigned int* xb = (unsigned int*)d_out;                       // bf16 ping buffer in d_out

    hipMemsetAsync(cnt, 0, (size_t)n * 4, stream);

    int enw = 8192; if (2 * E < enw) enw = 2 * E;
    int xnh = 16384; if (n * DF < xnh) xnh = n * DF;
    detect_flags_kernel<<<1, 256, 0, stream>>>((const unsigned int*)eidx, enw,
                                               (const unsigned short*)x, xnh, flagI, flagD);

    int nb = (n + 255) / 256;   // must be <= 512 for scan_partials
    // bucketed edge kernels: 8 buckets x 64 blocks; blockIdx&7 == bucket == (likely) XCD
    int ebgrid = 8 * 64;
    count_deg_kernel<<<ebgrid, 256, 0, stream>>>(eidx, flagI, E, n, cnt);
    dinv_kernel<<<nb, 256, 0, stream>>>(cnt, dinv, n);
    scan_blocks_kernel<<<nb, 256, 0, stream>>>(cnt, row_start, partials, n);
    scan_partials_kernel<<<1, 512, 0, stream>>>(partials, nb);
    finalize_rows_kernel<<<nb, 256, 0, stream>>>(row_start, partials, cnt, cursor, n);
    scatter_kernel<<<ebgrid, 256, 0, stream>>>(eidx, flagI, E, n, dinv, cursor, csr);

    // casts: x -> bf16 rows (in d_out space); W -> bf16, b -> fp32 (in ws)
    int nw2 = n * 32;  // uint2 count
    cast_x_kernel<<<(nw2 + 255) / 256, 256, 0, stream>>>(x, (uint2*)xb, flagD, nw2);
    cast_wb_kernel<<<64, 256, 0, stream>>>(W, b, Wb, bias_f, flagD);

    // hops ping-pong: xb(d_out) -> hb(ws) -> xb -> hb
    int hb_grid = (n + 3) / 4;
    hop_kernel<<<hb_grid, 256, 0, stream>>>((const uint4*)xb, (uint4*)hb, csr, row_start, dinv, n);
    hop_kernel<<<hb_grid, 256, 0, stream>>>((const uint4*)hb, (uint4*)xb, csr, row_start, dinv, n);
    hop_kernel<<<hb_grid, 256, 0, stream>>>((const uint4*)xb, (uint4*)hb, csr, row_start, dinv, n);

    // linear: reads hb (ws), writes full d_out (xb region is dead)
    int nstrips = (n + 15) / 16;
    int lgrid = 512; if ((nstrips + 3) / 4 < lgrid) lgrid = (nstrips + 3) / 4;
    linear_mfma_kernel<<<lgrid, 256, 0, stream>>>(
        (const unsigned short*)hb, Wb, bias_f, d_out, flagD, n);
}

// Round 5
// 330.527 us; speedup vs baseline: 1.1681x; 1.1681x over previous
//
#include <hip/hip_runtime.h>
#include <hip/hip_bf16.h>

#define DF 128

// flagI: 1 = edge_index stored as int64, 0 = int32
// flagD: 1 = x/W/b/out are bf16, 0 = fp32   (round-5 evidence: fp32 on this bench)

typedef __attribute__((ext_vector_type(8))) short shortx8;   // MFMA A/B frag (8 bf16)
typedef __attribute__((ext_vector_type(4))) float floatx4;   // MFMA C/D frag

__device__ __forceinline__ unsigned short f32_to_bf16_rne(float f) {
    unsigned int u = __float_as_uint(f);
    unsigned int r = (u >> 16) & 1u;
    u += 0x7FFFu + r;
    return (unsigned short)(u >> 16);
}
__device__ __forceinline__ float bf16_lo(unsigned int w) { return __uint_as_float(w << 16); }
__device__ __forceinline__ float bf16_hi(unsigned int w) { return __uint_as_float(w & 0xffff0000u); }
__device__ __forceinline__ unsigned int pack_bf16(float x, float y) {
    return ((unsigned int)f32_to_bf16_rne(y) << 16) | (unsigned int)f32_to_bf16_rne(x);
}

// ---------------- dtype detection ----------------
__global__ void detect_flags_kernel(const unsigned int* __restrict__ ew, int enwords,
                                    const unsigned short* __restrict__ xh, int xnh,
                                    int* __restrict__ flagI, int* __restrict__ flagD) {
    __shared__ int eodd_nz;
    __shared__ int xbig;
    if (threadIdx.x == 0) { eodd_nz = 0; xbig = 0; }
    __syncthreads();
    int f1 = 0;
    for (int i = 1 + 2 * (int)threadIdx.x; i < enwords; i += 2 * (int)blockDim.x)
        if (ew[i] != 0u) f1 = 1;
    int c = 0;
    for (int i = 2 * (int)threadIdx.x; i < xnh; i += 2 * (int)blockDim.x) {
        unsigned int e = ((unsigned int)xh[i] >> 7) & 0xFFu;
        if (e >= 0xC0u) c++;   // |v| >= 2^65 viewed as bf16 -> impossible for real data
    }
    if (f1) eodd_nz = 1;
    if (c) atomicAdd(&xbig, c);
    __syncthreads();
    if (threadIdx.x == 0) {
        *flagI = (eodd_nz == 0) ? 1 : 0;
        *flagD = (xbig > 8) ? 0 : 1;
    }
}

// ---------------- pass 1: degree count + per-edge rank (ONE atomic pass) ----------------
// The returning atomicAdd both counts the in-degree and assigns this edge its slot
// rank within the dst segment. 4 edges/thread -> 4 independent atomics in flight
// (the old scatter was latency-bound on one atomic chain per edge).
__global__ __launch_bounds__(256) void count_rank_kernel(const int* __restrict__ eidx,
                                                         const int* __restrict__ flagI,
                                                         int E, int n, int* __restrict__ cnt,
                                                         int* __restrict__ rank) {
    int t = blockIdx.x * blockDim.x + threadIdx.x;
    int base = t * 4;
    if (base >= E) return;
    int isI64 = *flagI;
    const long long* p64 = (const long long*)eidx;
    int s[4], d[4];
#pragma unroll
    for (int j = 0; j < 4; ++j) {
        int e = base + j;
        if (e < E) {
            if (isI64) { s[j] = (int)p64[e]; d[j] = (int)p64[(long long)E + e]; }
            else       { s[j] = eidx[e];     d[j] = eidx[E + e]; }
        } else { s[j] = -1; d[j] = -1; }
    }
    int r[4];
#pragma unroll
    for (int j = 0; j < 4; ++j) {
        bool ok = ((unsigned)d[j] < (unsigned)n) && ((unsigned)s[j] < (unsigned)n);
        r[j] = ok ? atomicAdd(&cnt[d[j]], 1) : 0;
    }
    if (base + 3 < E) {
        *(int4*)&rank[base] = make_int4(r[0], r[1], r[2], r[3]);
    } else {
#pragma unroll
        for (int j = 0; j < 4; ++j)
            if (base + j < E) rank[base + j] = r[j];
    }
}

// ---------------- exclusive scan of cnt -> row_start ----------------
__global__ void scan_blocks_kernel(const int* __restrict__ cnt, int* __restrict__ row_start,
                                   int* __restrict__ partials, int n) {
    __shared__ int s[256];
    int i = blockIdx.x * 256 + threadIdx.x;
    int v = (i < n) ? cnt[i] : 0;
    s[threadIdx.x] = v;
    __syncthreads();
    for (int off = 1; off < 256; off <<= 1) {
        int t = ((int)threadIdx.x >= off) ? s[threadIdx.x - off] : 0;
        __syncthreads();
        s[threadIdx.x] += t;
        __syncthreads();
    }
    if (i < n) row_start[i] = s[threadIdx.x] - v;
    if (threadIdx.x == 255) partials[blockIdx.x] = s[255];
}

__global__ void scan_partials_kernel(int* __restrict__ partials, int nparts) {
    __shared__ int s[512];
    int v = ((int)threadIdx.x < nparts) ? partials[threadIdx.x] : 0;
    s[threadIdx.x] = v;
    __syncthreads();
    for (int off = 1; off < 512; off <<= 1) {
        int t = ((int)threadIdx.x >= off) ? s[threadIdx.x - off] : 0;
        __syncthreads();
        s[threadIdx.x] += t;
        __syncthreads();
    }
    if ((int)threadIdx.x < nparts) partials[threadIdx.x] = s[threadIdx.x] - v;
}

// finalize rows + fused dinv (one fewer dispatch)
__global__ void finalize_rows_kernel(int* __restrict__ row_start, const int* __restrict__ partials,
                                     const int* __restrict__ cnt, float* __restrict__ dinv, int n) {
    int i = blockIdx.x * 256 + threadIdx.x;
    if (i < n) {
        int r = row_start[i] + partials[blockIdx.x];
        row_start[i] = r;
        dinv[i] = rsqrtf((float)(cnt[i] + 1));
        if (i == n - 1) row_start[n] = r + cnt[i];
    }
}

// ---------------- pass 2: ATOMIC-FREE CSR scatter ----------------
// pos = row_start[d] + rank[e]; purely independent loads + one 8B store per edge,
// 4 edges/thread for ILP. (Old version: returning atomic -> dependent scattered
// store, latency-bound at 56us / 13% HBM.)
__global__ __launch_bounds__(256) void scatter_kernel(const int* __restrict__ eidx,
                                                      const int* __restrict__ flagI,
                                                      const int* __restrict__ rank,
                                                      const int* __restrict__ row_start,
                                                      int E, int n, const float* __restrict__ dinv,
                                                      int2* __restrict__ csr) {
    int t = blockIdx.x * blockDim.x + threadIdx.x;
    int base = t * 4;
    if (base >= E) return;
    int isI64 = *flagI;
    const long long* p64 = (const long long*)eidx;
    int s[4], d[4], r[4];
    if (base + 3 < E) {
        int4 rv = *(const int4*)&rank[base];
        r[0] = rv.x; r[1] = rv.y; r[2] = rv.z; r[3] = rv.w;
#pragma unroll
        for (int j = 0; j < 4; ++j) {
            int e = base + j;
            if (isI64) { s[j] = (int)p64[e]; d[j] = (int)p64[(long long)E + e]; }
            else       { s[j] = eidx[e];     d[j] = eidx[E + e]; }
        }
    } else {
#pragma unroll
        for (int j = 0; j < 4; ++j) {
            int e = base + j;
            if (e < E) {
                r[j] = rank[e];
                if (isI64) { s[j] = (int)p64[e]; d[j] = (int)p64[(long long)E + e]; }
                else       { s[j] = eidx[e];     d[j] = eidx[E + e]; }
            } else { s[j] = -1; d[j] = -1; r[j] = 0; }
        }
    }
#pragma unroll
    for (int j = 0; j < 4; ++j) {
        bool ok = ((unsigned)d[j] < (unsigned)n) && ((unsigned)s[j] < (unsigned)n);
        if (ok) {
            int pos = row_start[d[j]] + r[j];
            int2 pk;
            pk.x = s[j];
            pk.y = __float_as_int(dinv[s[j]]);
            csr[pos] = pk;
        }
    }
}

// ---------------- cast x -> packed bf16 rows (or copy if already bf16) ----------------
__global__ void cast_x_kernel(const void* __restrict__ x, uint2* __restrict__ xb,
                              const int* __restrict__ flagD, int nw2) {
    int i = blockIdx.x * blockDim.x + threadIdx.x;
    if (i >= nw2) return;
    if (*flagD) {
        xb[i] = ((const uint2*)x)[i];
    } else {
        float4 v = ((const float4*)x)[i];
        uint2 o;
        o.x = pack_bf16(v.x, v.y);
        o.y = pack_bf16(v.z, v.w);
        xb[i] = o;
    }
}

// ---------------- cast W -> bf16 (once), b -> fp32 (once) ----------------
__global__ void cast_wb_kernel(const void* __restrict__ W, const void* __restrict__ b,
                               unsigned short* __restrict__ Wb, float* __restrict__ bias_f,
                               const int* __restrict__ flagD) {
    int i = blockIdx.x * 256 + threadIdx.x;
    int bf = *flagD;
    if (i < 128 * 128)
        Wb[i] = bf ? ((const unsigned short*)W)[i] : f32_to_bf16_rne(((const float*)W)[i]);
    if (i < 128)
        bias_f[i] = bf ? bf16_lo((unsigned int)((const unsigned short*)b)[i]) : ((const float*)b)[i];
}

// ---------------- hop: one wave per node, quarter-wave uint4 gathers ----------------
// lane = 16*e + c (e: edge slot 0..3, c: 16B chunk 0..15). Each iteration gathers
// 4 edge-rows with ONE dwordx4 per lane; fp32 accumulate 8 cols/lane; shfl-xor
// reduce across quarters; quarter 0 stores the 256B row.
// out[i] = di*(di*self + sum_s dinv[s]*h[s])
__global__ __launch_bounds__(256) void hop_kernel(const uint4* __restrict__ hin,
                                                  uint4* __restrict__ hout,
                                                  const int2* __restrict__ csr,
                                                  const int* __restrict__ row_start,
                                                  const float* __restrict__ dinv, int n) {
    int gw = (int)((blockIdx.x * 256 + threadIdx.x) >> 6);
    int lane = (int)(threadIdx.x & 63);
    if (gw >= n) return;
    int e = lane >> 4, c = lane & 15;
    float di = dinv[gw];
    int beg = row_start[gw], end = row_start[gw + 1];
    uint4 sv = hin[(size_t)gw * 16 + c];     // self row (broadcast across quarters)
    float a0 = 0.f, a1 = 0.f, a2 = 0.f, a3 = 0.f, a4 = 0.f, a5 = 0.f, a6 = 0.f, a7 = 0.f;
    for (int j = beg + e; j < end; j += 4) {
        int2 ed = csr[j];
        float w = __int_as_float(ed.y);
        uint4 v = hin[(size_t)ed.x * 16 + c];
        a0 += w * bf16_lo(v.x); a1 += w * bf16_hi(v.x);
        a2 += w * bf16_lo(v.y); a3 += w * bf16_hi(v.y);
        a4 += w * bf16_lo(v.z); a5 += w * bf16_hi(v.z);
        a6 += w * bf16_lo(v.w); a7 += w * bf16_hi(v.w);
    }
    // reduce the 4 quarter-partials for each column set
    a0 += __shfl_xor(a0, 16); a0 += __shfl_xor(a0, 32);
    a1 += __shfl_xor(a1, 16); a1 += __shfl_xor(a1, 32);
    a2 += __shfl_xor(a2, 16); a2 += __shfl_xor(a2, 32);
    a3 += __shfl_xor(a3, 16); a3 += __shfl_xor(a3, 32);
    a4 += __shfl_xor(a4, 16); a4 += __shfl_xor(a4, 32);
    a5 += __shfl_xor(a5, 16); a5 += __shfl_xor(a5, 32);
    a6 += __shfl_xor(a6, 16); a6 += __shfl_xor(a6, 32);
    a7 += __shfl_xor(a7, 16); a7 += __shfl_xor(a7, 32);
    // add self term and final scale
    a0 = di * (a0 + di * bf16_lo(sv.x)); a1 = di * (a1 + di * bf16_hi(sv.x));
    a2 = di * (a2 + di * bf16_lo(sv.y)); a3 = di * (a3 + di * bf16_hi(sv.y));
    a4 = di * (a4 + di * bf16_lo(sv.z)); a5 = di * (a5 + di * bf16_hi(sv.z));
    a6 = di * (a6 + di * bf16_lo(sv.w)); a7 = di * (a7 + di * bf16_hi(sv.w));
    if (e == 0) {
        uint4 o;
        o.x = pack_bf16(a0, a1);
        o.y = pack_bf16(a2, a3);
        o.z = pack_bf16(a4, a5);
        o.w = pack_bf16(a6, a7);
        hout[(size_t)gw * 16 + c] = o;
    }
}

// ---------------- MFMA linear: out = h @ Wb^T + bias (h,Wb bf16; out per flagD) ----------------
// 16x16x32 bf16 MFMA. A: lane holds A[m=lane&15][k=q*8+j], q=lane>>4.
// B: lane holds B[k=q*8+j][o=lane&15]. C/D: col=lane&15, row=q*4+reg.
// Grid-stride over 16-row strips so W-frag setup is amortized.
__global__ __launch_bounds__(256, 2) void linear_mfma_kernel(
        const unsigned short* __restrict__ h, const unsigned short* __restrict__ Wb,
        const float* __restrict__ bias_f, void* __restrict__ out,
        const int* __restrict__ flagD, int n) {
    int bf = *flagD;
    int wave = (int)(threadIdx.x >> 6);
    int lane = (int)(threadIdx.x & 63);
    int q = lane >> 4, m16 = lane & 15;

    shortx8 bfrag[8][4];
    float bias[8];
#pragma unroll
    for (int nt = 0; nt < 8; ++nt) {
        int wr = nt * 16 + m16;               // W row = output feature o
#pragma unroll
        for (int t = 0; t < 4; ++t)
            bfrag[nt][t] = *(const shortx8*)&Wb[wr * 128 + t * 32 + q * 8];
        bias[nt] = bias_f[wr];
    }

    int nstrips = (n + 15) / 16;
    int wid = (int)blockIdx.x * 4 + wave;
    int nw = (int)gridDim.x * 4;
    for (int s = wid; s < nstrips; s += nw) {
        int row0 = s * 16;
        int arow = row0 + m16;
        if (arow >= n) arow = n - 1;          // clamp (dup rows; stores guarded)
        shortx8 afrag[4];
#pragma unroll
        for (int t = 0; t < 4; ++t)
            afrag[t] = *(const shortx8*)&h[(size_t)arow * 128 + t * 32 + q * 8];

        floatx4 acc[8];
#pragma unroll
        for (int nt = 0; nt < 8; ++nt) acc[nt] = (floatx4){0.f, 0.f, 0.f, 0.f};
#pragma unroll
        for (int t = 0; t < 4; ++t)
#pragma unroll
            for (int nt = 0; nt < 8; ++nt)
                acc[nt] = __builtin_amdgcn_mfma_f32_16x16x32_bf16(afrag[t], bfrag[nt][t], acc[nt], 0, 0, 0);

#pragma unroll
        for (int nt = 0; nt < 8; ++nt)
#pragma unroll
            for (int r = 0; r < 4; ++r) {
                int row = row0 + q * 4 + r;
                if (row < n) {
                    float v = acc[nt][r] + bias[nt];
                    size_t oi = (size_t)row * 128 + nt * 16 + m16;
                    if (bf) ((unsigned short*)out)[oi] = f32_to_bf16_rne(v);
                    else    ((float*)out)[oi] = v;
                }
            }
    }
}

extern "C" void kernel_launch(void* const* d_in, const int* in_sizes, int n_in,
                              void* d_out, int out_size, void* d_ws, size_t ws_size,
                              hipStream_t stream) {
    const void* x = d_in[0];
    const int* eidx = (const int*)d_in[1];
    const void* W = d_in[2];
    const void* b = d_in[3];

    int n = in_sizes[0] / DF;   // 100000
    int E = in_sizes[1] / 2;    // 800000

    // workspace carve-up (~37 MB; d_out hosts the second bf16 ping buffer,
    // safe because out_size*2B >= 25.6MB even for bf16 output)
    char* ws = (char*)d_ws;
    size_t off = 0;
    auto alloc = [&](size_t bytes) -> void* {
        void* p = ws + off;
        off = (off + bytes + 255) & ~(size_t)255;
        return p;
    };
    unsigned int* hb = (unsigned int*)alloc((size_t)n * 64 * 4);   // bf16 rows, 25.6MB
    float* dinv      = (float*)alloc((size_t)n * 4);
    int*   cnt       = (int*)alloc((size_t)n * 4);
    int*   row_start = (int*)alloc((size_t)(n + 1) * 4);
    int*   partials  = (int*)alloc(4096);
    int*   flagI     = (int*)alloc(256);
    int*   flagD     = (int*)alloc(256);
    unsigned short* Wb = (unsigned short*)alloc(128 * 128 * 2);    // bf16 W
    float* bias_f    = (float*)alloc(128 * 4);
    int2*  csr       = (int2*)alloc((size_t)E * 8);                // {src, dinv[src]}
    int*   rank      = (int*)alloc((size_t)E * 4);                 // per-edge slot rank
    unsigned int* xb = (unsigned int*)d_out;                       // bf16 ping buffer in d_out

    hipMemsetAsync(cnt, 0, (size_t)n * 4, stream);

    int enw = 8192; if (2 * E < enw) enw = 2 * E;
    int xnh = 16384; if (n * DF < xnh) xnh = n * DF;
    detect_flags_kernel<<<1, 256, 0, stream>>>((const unsigned int*)eidx, enw,
                                               (const unsigned short*)x, xnh, flagI, flagD);

    int nb = (n + 255) / 256;   // must be <= 512 for scan_partials
    int e4 = (E + 3) / 4;                       // threads (4 edges each)
    int ebgrid = (e4 + 255) / 256;
    count_rank_kernel<<<ebgrid, 256, 0, stream>>>(eidx, flagI, E, n, cnt, rank);
    scan_blocks_kernel<<<nb, 256, 0, stream>>>(cnt, row_start, partials, n);
    scan_partials_kernel<<<1, 512, 0, stream>>>(partials, nb);
    finalize_rows_kernel<<<nb, 256, 0, stream>>>(row_start, partials, cnt, dinv, n);
    scatter_kernel<<<ebgrid, 256, 0, stream>>>(eidx, flagI, rank, row_start, E, n, dinv, csr);

    // casts: x -> bf16 rows (in d_out space); W -> bf16, b -> fp32 (in ws)
    int nw2 = n * 32;  // uint2 count
    cast_x_kernel<<<(nw2 + 255) / 256, 256, 0, stream>>>(x, (uint2*)xb, flagD, nw2);
    cast_wb_kernel<<<64, 256, 0, stream>>>(W, b, Wb, bias_f, flagD);

    // hops ping-pong: xb(d_out) -> hb(ws) -> xb -> hb
    int hb_grid = (n + 3) / 4;
    hop_kernel<<<hb_grid, 256, 0, stream>>>((const uint4*)xb, (uint4*)hb, csr, row_start, dinv, n);
    hop_kernel<<<hb_grid, 256, 0, stream>>>((const uint4*)hb, (uint4*)xb, csr, row_start, dinv, n);
    hop_kernel<<<hb_grid, 256, 0, stream>>>((const uint4*)xb, (uint4*)hb, csr, row_start, dinv, n);

    // linear: reads hb (ws), writes full d_out (xb region is dead)
    int nstrips = (n + 15) / 16;
    int lgrid = 512; if ((nstrips + 3) / 4 < lgrid) lgrid = (nstrips + 3) / 4;
    linear_mfma_kernel<<<lgrid, 256, 0, stream>>>(
        (const unsigned short*)hb, Wb, bias_f, d_out, flagD, n);
}

// Round 7
// 324.968 us; speedup vs baseline: 1.1881x; 1.0171x over previous
//
#include <hip/hip_runtime.h>
#include <hip/hip_bf16.h>

#define DF 128

// flagI: 1 = edge_index stored as int64, 0 = int32
// flagD: 1 = x/W/b/out are bf16, 0 = fp32   (round-5 evidence: fp32 on this bench)

typedef __attribute__((ext_vector_type(8))) short shortx8;   // MFMA A/B frag (8 bf16)
typedef __attribute__((ext_vector_type(4))) float floatx4;   // MFMA C/D frag

__device__ __forceinline__ unsigned short f32_to_bf16_rne(float f) {
    unsigned int u = __float_as_uint(f);
    unsigned int r = (u >> 16) & 1u;
    u += 0x7FFFu + r;
    return (unsigned short)(u >> 16);
}
__device__ __forceinline__ float bf16_lo(unsigned int w) { return __uint_as_float(w << 16); }
__device__ __forceinline__ float bf16_hi(unsigned int w) { return __uint_as_float(w & 0xffff0000u); }
__device__ __forceinline__ unsigned int pack_bf16(float x, float y) {
    return ((unsigned int)f32_to_bf16_rne(y) << 16) | (unsigned int)f32_to_bf16_rne(x);
}

// ---------------- dtype detection ----------------
__global__ void detect_flags_kernel(const unsigned int* __restrict__ ew, int enwords,
                                    const unsigned short* __restrict__ xh, int xnh,
                                    int* __restrict__ flagI, int* __restrict__ flagD) {
    __shared__ int eodd_nz;
    __shared__ int xbig;
    if (threadIdx.x == 0) { eodd_nz = 0; xbig = 0; }
    __syncthreads();
    int f1 = 0;
    for (int i = 1 + 2 * (int)threadIdx.x; i < enwords; i += 2 * (int)blockDim.x)
        if (ew[i] != 0u) f1 = 1;
    int c = 0;
    for (int i = 2 * (int)threadIdx.x; i < xnh; i += 2 * (int)blockDim.x) {
        unsigned int e = ((unsigned int)xh[i] >> 7) & 0xFFu;
        if (e >= 0xC0u) c++;   // |v| >= 2^65 viewed as bf16 -> impossible for real data
    }
    if (f1) eodd_nz = 1;
    if (c) atomicAdd(&xbig, c);
    __syncthreads();
    if (threadIdx.x == 0) {
        *flagI = (eodd_nz == 0) ? 1 : 0;
        *flagD = (xbig > 8) ? 0 : 1;
    }
}

// ---------------- pass 1: degree count + per-edge rank (ONE atomic pass) ----------------
__global__ __launch_bounds__(256) void count_rank_kernel(const int* __restrict__ eidx,
                                                         const int* __restrict__ flagI,
                                                         int E, int n, int* __restrict__ cnt,
                                                         int* __restrict__ rank) {
    int t = blockIdx.x * blockDim.x + threadIdx.x;
    int base = t * 4;
    if (base >= E) return;
    int isI64 = *flagI;
    const long long* p64 = (const long long*)eidx;
    int s[4], d[4];
#pragma unroll
    for (int j = 0; j < 4; ++j) {
        int e = base + j;
        if (e < E) {
            if (isI64) { s[j] = (int)p64[e]; d[j] = (int)p64[(long long)E + e]; }
            else       { s[j] = eidx[e];     d[j] = eidx[E + e]; }
        } else { s[j] = -1; d[j] = -1; }
    }
    int r[4];
#pragma unroll
    for (int j = 0; j < 4; ++j) {
        bool ok = ((unsigned)d[j] < (unsigned)n) && ((unsigned)s[j] < (unsigned)n);
        r[j] = ok ? atomicAdd(&cnt[d[j]], 1) : 0;
    }
    if (base + 3 < E) {
        *(int4*)&rank[base] = make_int4(r[0], r[1], r[2], r[3]);
    } else {
#pragma unroll
        for (int j = 0; j < 4; ++j)
            if (base + j < E) rank[base + j] = r[j];
    }
}

// ---------------- exclusive scan of cnt -> row_start ----------------
__global__ void scan_blocks_kernel(const int* __restrict__ cnt, int* __restrict__ row_start,
                                   int* __restrict__ partials, int n) {
    __shared__ int s[256];
    int i = blockIdx.x * 256 + threadIdx.x;
    int v = (i < n) ? cnt[i] : 0;
    s[threadIdx.x] = v;
    __syncthreads();
    for (int off = 1; off < 256; off <<= 1) {
        int t = ((int)threadIdx.x >= off) ? s[threadIdx.x - off] : 0;
        __syncthreads();
        s[threadIdx.x] += t;
        __syncthreads();
    }
    if (i < n) row_start[i] = s[threadIdx.x] - v;
    if (threadIdx.x == 255) partials[blockIdx.x] = s[255];
}

__global__ void scan_partials_kernel(int* __restrict__ partials, int nparts) {
    __shared__ int s[512];
    int v = ((int)threadIdx.x < nparts) ? partials[threadIdx.x] : 0;
    s[threadIdx.x] = v;
    __syncthreads();
    for (int off = 1; off < 512; off <<= 1) {
        int t = ((int)threadIdx.x >= off) ? s[threadIdx.x - off] : 0;
        __syncthreads();
        s[threadIdx.x] += t;
        __syncthreads();
    }
    if ((int)threadIdx.x < nparts) partials[threadIdx.x] = s[threadIdx.x] - v;
}

// finalize rows + fused dinv (one fewer dispatch)
__global__ void finalize_rows_kernel(int* __restrict__ row_start, const int* __restrict__ partials,
                                     const int* __restrict__ cnt, float* __restrict__ dinv, int n) {
    int i = blockIdx.x * 256 + threadIdx.x;
    if (i < n) {
        int r = row_start[i] + partials[blockIdx.x];
        row_start[i] = r;
        dinv[i] = rsqrtf((float)(cnt[i] + 1));
        if (i == n - 1) row_start[n] = r + cnt[i];
    }
}

// ---------------- pass 2: ATOMIC-FREE CSR scatter ----------------
__global__ __launch_bounds__(256) void scatter_kernel(const int* __restrict__ eidx,
                                                      const int* __restrict__ flagI,
                                                      const int* __restrict__ rank,
                                                      const int* __restrict__ row_start,
                                                      int E, int n, const float* __restrict__ dinv,
                                                      int2* __restrict__ csr) {
    int t = blockIdx.x * blockDim.x + threadIdx.x;
    int base = t * 4;
    if (base >= E) return;
    int isI64 = *flagI;
    const long long* p64 = (const long long*)eidx;
    int s[4], d[4], r[4];
    if (base + 3 < E) {
        int4 rv = *(const int4*)&rank[base];
        r[0] = rv.x; r[1] = rv.y; r[2] = rv.z; r[3] = rv.w;
#pragma unroll
        for (int j = 0; j < 4; ++j) {
            int e = base + j;
            if (isI64) { s[j] = (int)p64[e]; d[j] = (int)p64[(long long)E + e]; }
            else       { s[j] = eidx[e];     d[j] = eidx[E + e]; }
        }
    } else {
#pragma unroll
        for (int j = 0; j < 4; ++j) {
            int e = base + j;
            if (e < E) {
                r[j] = rank[e];
                if (isI64) { s[j] = (int)p64[e]; d[j] = (int)p64[(long long)E + e]; }
                else       { s[j] = eidx[e];     d[j] = eidx[E + e]; }
            } else { s[j] = -1; d[j] = -1; r[j] = 0; }
        }
    }
#pragma unroll
    for (int j = 0; j < 4; ++j) {
        bool ok = ((unsigned)d[j] < (unsigned)n) && ((unsigned)s[j] < (unsigned)n);
        if (ok) {
            int pos = row_start[d[j]] + r[j];
            int2 pk;
            pk.x = s[j];
            pk.y = __float_as_int(dinv[s[j]]);
            csr[pos] = pk;
        }
    }
}

// ---------------- cast x -> packed bf16 rows (or copy if already bf16) ----------------
__global__ void cast_x_kernel(const void* __restrict__ x, uint2* __restrict__ xb,
                              const int* __restrict__ flagD, int nw2) {
    int i = blockIdx.x * blockDim.x + threadIdx.x;
    if (i >= nw2) return;
    if (*flagD) {
        xb[i] = ((const uint2*)x)[i];
    } else {
        float4 v = ((const float4*)x)[i];
        uint2 o;
        o.x = pack_bf16(v.x, v.y);
        o.y = pack_bf16(v.z, v.w);
        xb[i] = o;
    }
}

// ---------------- cast W -> bf16 (once), b -> fp32 (once) ----------------
__global__ void cast_wb_kernel(const void* __restrict__ W, const void* __restrict__ b,
                               unsigned short* __restrict__ Wb, float* __restrict__ bias_f,
                               const int* __restrict__ flagD) {
    int i = blockIdx.x * 256 + threadIdx.x;
    int bf = *flagD;
    if (i < 128 * 128)
        Wb[i] = bf ? ((const unsigned short*)W)[i] : f32_to_bf16_rne(((const float*)W)[i]);
    if (i < 128)
        bias_f[i] = bf ? bf16_lo((unsigned int)((const unsigned short*)b)[i]) : ((const float*)b)[i];
}

// ---------------- hop: one wave per node, quarter-wave uint4 gathers, 2x-MLP ----------------
// lane = 16*e + c (e: edge slot 0..3, c: 16B chunk 0..15). 2x-unrolled loop: each
// iteration loads TWO csr entries and issues TWO independent 256B row gathers before
// the fmas (8 gathers in flight per wave vs 4 before — round-5 counters showed hop
// latency-bound: 2.93 TB/s / 37% HBM, VALUBusy 45%, neither pipe saturated).
// Tail re-gathers ed0 with weight 0 (L1-hit, harmless).
// out[i] = di*(di*self + sum_s dinv[s]*h[s])
__global__ __launch_bounds__(256) void hop_kernel(const uint4* __restrict__ hin,
                                                  uint4* __restrict__ hout,
                                                  const int2* __restrict__ csr,
                                                  const int* __restrict__ row_start,
                                                  const float* __restrict__ dinv, int n) {
    int gw = (int)((blockIdx.x * 256 + threadIdx.x) >> 6);
    int lane = (int)(threadIdx.x & 63);
    if (gw >= n) return;
    int e = lane >> 4, c = lane & 15;
    float di = dinv[gw];
    int beg = row_start[gw], end = row_start[gw + 1];
    uint4 sv = hin[(size_t)gw * 16 + c];     // self row (broadcast across quarters)
    float a0 = 0.f, a1 = 0.f, a2 = 0.f, a3 = 0.f, a4 = 0.f, a5 = 0.f, a6 = 0.f, a7 = 0.f;
    for (int j = beg + e; j < end; j += 8) {
        int2 ed0 = csr[j];
        bool has1 = (j + 4) < end;
        int2 ed1 = has1 ? csr[j + 4] : ed0;
        uint4 v0 = hin[(size_t)ed0.x * 16 + c];          // two independent gathers
        uint4 v1 = hin[(size_t)ed1.x * 16 + c];          // in flight concurrently
        float w0 = __int_as_float(ed0.y);
        float w1 = has1 ? __int_as_float(ed1.y) : 0.f;
        a0 += w0 * bf16_lo(v0.x); a1 += w0 * bf16_hi(v0.x);
        a2 += w0 * bf16_lo(v0.y); a3 += w0 * bf16_hi(v0.y);
        a4 += w0 * bf16_lo(v0.z); a5 += w0 * bf16_hi(v0.z);
        a6 += w0 * bf16_lo(v0.w); a7 += w0 * bf16_hi(v0.w);
        a0 += w1 * bf16_lo(v1.x); a1 += w1 * bf16_hi(v1.x);
        a2 += w1 * bf16_lo(v1.y); a3 += w1 * bf16_hi(v1.y);
        a4 += w1 * bf16_lo(v1.z); a5 += w1 * bf16_hi(v1.z);
        a6 += w1 * bf16_lo(v1.w); a7 += w1 * bf16_hi(v1.w);
    }
    // reduce the 4 quarter-partials for each column set
    a0 += __shfl_xor(a0, 16); a0 += __shfl_xor(a0, 32);
    a1 += __shfl_xor(a1, 16); a1 += __shfl_xor(a1, 32);
    a2 += __shfl_xor(a2, 16); a2 += __shfl_xor(a2, 32);
    a3 += __shfl_xor(a3, 16); a3 += __shfl_xor(a3, 32);
    a4 += __shfl_xor(a4, 16); a4 += __shfl_xor(a4, 32);
    a5 += __shfl_xor(a5, 16); a5 += __shfl_xor(a5, 32);
    a6 += __shfl_xor(a6, 16); a6 += __shfl_xor(a6, 32);
    a7 += __shfl_xor(a7, 16); a7 += __shfl_xor(a7, 32);
    // add self term and final scale
    a0 = di * (a0 + di * bf16_lo(sv.x)); a1 = di * (a1 + di * bf16_hi(sv.x));
    a2 = di * (a2 + di * bf16_lo(sv.y)); a3 = di * (a3 + di * bf16_hi(sv.y));
    a4 = di * (a4 + di * bf16_lo(sv.z)); a5 = di * (a5 + di * bf16_hi(sv.z));
    a6 = di * (a6 + di * bf16_lo(sv.w)); a7 = di * (a7 + di * bf16_hi(sv.w));
    if (e == 0) {
        uint4 o;
        o.x = pack_bf16(a0, a1);
        o.y = pack_bf16(a2, a3);
        o.z = pack_bf16(a4, a5);
        o.w = pack_bf16(a6, a7);
        hout[(size_t)gw * 16 + c] = o;
    }
}

// ---------------- MFMA linear: out = h @ Wb^T + bias (h,Wb bf16; out per flagD) ----------------
__global__ __launch_bounds__(256, 2) void linear_mfma_kernel(
        const unsigned short* __restrict__ h, const unsigned short* __restrict__ Wb,
        const float* __restrict__ bias_f, void* __restrict__ out,
        const int* __restrict__ flagD, int n) {
    int bf = *flagD;
    int wave = (int)(threadIdx.x >> 6);
    int lane = (int)(threadIdx.x & 63);
    int q = lane >> 4, m16 = lane & 15;

    shortx8 bfrag[8][4];
    float bias[8];
#pragma unroll
    for (int nt = 0; nt < 8; ++nt) {
        int wr = nt * 16 + m16;               // W row = output feature o
#pragma unroll
        for (int t = 0; t < 4; ++t)
            bfrag[nt][t] = *(const shortx8*)&Wb[wr * 128 + t * 32 + q * 8];
        bias[nt] = bias_f[wr];
    }

    int nstrips = (n + 15) / 16;
    int wid = (int)blockIdx.x * 4 + wave;
    int nw = (int)gridDim.x * 4;
    for (int s = wid; s < nstrips; s += nw) {
        int row0 = s * 16;
        int arow = row0 + m16;
        if (arow >= n) arow = n - 1;          // clamp (dup rows; stores guarded)
        shortx8 afrag[4];
#pragma unroll
        for (int t = 0; t < 4; ++t)
            afrag[t] = *(const shortx8*)&h[(size_t)arow * 128 + t * 32 + q * 8];

        floatx4 acc[8];
#pragma unroll
        for (int nt = 0; nt < 8; ++nt) acc[nt] = (floatx4){0.f, 0.f, 0.f, 0.f};
#pragma unroll
        for (int t = 0; t < 4; ++t)
#pragma unroll
            for (int nt = 0; nt < 8; ++nt)
                acc[nt] = __builtin_amdgcn_mfma_f32_16x16x32_bf16(afrag[t], bfrag[nt][t], acc[nt], 0, 0, 0);

#pragma unroll
        for (int nt = 0; nt < 8; ++nt)
#pragma unroll
            for (int r = 0; r < 4; ++r) {
                int row = row0 + q * 4 + r;
                if (row < n) {
                    float v = acc[nt][r] + bias[nt];
                    size_t oi = (size_t)row * 128 + nt * 16 + m16;
                    if (bf) ((unsigned short*)out)[oi] = f32_to_bf16_rne(v);
                    else    ((float*)out)[oi] = v;
                }
            }
    }
}

extern "C" void kernel_launch(void* const* d_in, const int* in_sizes, int n_in,
                              void* d_out, int out_size, void* d_ws, size_t ws_size,
                              hipStream_t stream) {
    const void* x = d_in[0];
    const int* eidx = (const int*)d_in[1];
    const void* W = d_in[2];
    const void* b = d_in[3];

    int n = in_sizes[0] / DF;   // 100000
    int E = in_sizes[1] / 2;    // 800000

    // workspace carve-up (~37 MB; d_out hosts the second bf16 ping buffer,
    // safe because out_size*2B >= 25.6MB even for bf16 output)
    char* ws = (char*)d_ws;
    size_t off = 0;
    auto alloc = [&](size_t bytes) -> void* {
        void* p = ws + off;
        off = (off + bytes + 255) & ~(size_t)255;
        return p;
    };
    unsigned int* hb = (unsigned int*)alloc((size_t)n * 64 * 4);   // bf16 rows, 25.6MB
    float* dinv      = (float*)alloc((size_t)n * 4);
    int*   cnt       = (int*)alloc((size_t)n * 4);
    int*   row_start = (int*)alloc((size_t)(n + 1) * 4);
    int*   partials  = (int*)alloc(4096);
    int*   flagI     = (int*)alloc(256);
    int*   flagD     = (int*)alloc(256);
    unsigned short* Wb = (unsigned short*)alloc(128 * 128 * 2);    // bf16 W
    float* bias_f    = (float*)alloc(128 * 4);
    int2*  csr       = (int2*)alloc((size_t)E * 8);                // {src, dinv[src]}
    int*   rank      = (int*)alloc((size_t)E * 4);                 // per-edge slot rank
    unsigned int* xb = (unsigned int*)d_out;                       // bf16 ping buffer in d_out

    hipMemsetAsync(cnt, 0, (size_t)n * 4, stream);

    int enw = 8192; if (2 * E < enw) enw = 2 * E;
    int xnh = 16384; if (n * DF < xnh) xnh = n * DF;
    detect_flags_kernel<<<1, 256, 0, stream>>>((const unsigned int*)eidx, enw,
                                               (const unsigned short*)x, xnh, flagI, flagD);

    int nb = (n + 255) / 256;   // must be <= 512 for scan_partials
    int e4 = (E + 3) / 4;                       // threads (4 edges each)
    int ebgrid = (e4 + 255) / 256;
    count_rank_kernel<<<ebgrid, 256, 0, stream>>>(eidx, flagI, E, n, cnt, rank);
    scan_blocks_kernel<<<nb, 256, 0, stream>>>(cnt, row_start, partials, n);
    scan_partials_kernel<<<1, 512, 0, stream>>>(partials, nb);
    finalize_rows_kernel<<<nb, 256, 0, stream>>>(row_start, partials, cnt, dinv, n);
    scatter_kernel<<<ebgrid, 256, 0, stream>>>(eidx, flagI, rank, row_start, E, n, dinv, csr);

    // casts: x -> bf16 rows (in d_out space); W -> bf16, b -> fp32 (in ws)
    int nw2 = n * 32;  // uint2 count
    cast_x_kernel<<<(nw2 + 255) / 256, 256, 0, stream>>>(x, (uint2*)xb, flagD, nw2);
    cast_wb_kernel<<<64, 256, 0, stream>>>(W, b, Wb, bias_f, flagD);

    // hops ping-pong: xb(d_out) -> hb(ws) -> xb -> hb
    int hb_grid = (n + 3) / 4;
    hop_kernel<<<hb_grid, 256, 0, stream>>>((const uint4*)xb, (uint4*)hb, csr, row_start, dinv, n);
    hop_kernel<<<hb_grid, 256, 0, stream>>>((const uint4*)hb, (uint4*)xb, csr, row_start, dinv, n);
    hop_kernel<<<hb_grid, 256, 0, stream>>>((const uint4*)xb, (uint4*)hb, csr, row_start, dinv, n);

    // linear: reads hb (ws), writes full d_out (xb region is dead)
    int nstrips = (n + 15) / 16;
    int lgrid = 512; if ((nstrips + 3) / 4 < lgrid) lgrid = (nstrips + 3) / 4;
    linear_mfma_kernel<<<lgrid, 256, 0, stream>>>(
        (const unsigned short*)hb, Wb, bias_f, d_out, flagD, n);
}

// Round 9
// 317.189 us; speedup vs baseline: 1.2172x; 1.0245x over previous
//
#include <hip/hip_runtime.h>
#include <hip/hip_bf16.h>

#define DF 128

// flagI: 1 = edge_index stored as int64, 0 = int32
// flagD: 1 = x/W/b/out are bf16, 0 = fp32   (round-5 evidence: fp32 on this bench)

typedef __attribute__((ext_vector_type(8))) short shortx8;   // MFMA A/B frag (8 bf16)
typedef __attribute__((ext_vector_type(4))) float floatx4;   // MFMA C/D frag

__device__ __forceinline__ unsigned short f32_to_bf16_rne(float f) {
    unsigned int u = __float_as_uint(f);
    unsigned int r = (u >> 16) & 1u;
    u += 0x7FFFu + r;
    return (unsigned short)(u >> 16);
}
__device__ __forceinline__ float bf16_lo(unsigned int w) { return __uint_as_float(w << 16); }
__device__ __forceinline__ float bf16_hi(unsigned int w) { return __uint_as_float(w & 0xffff0000u); }
__device__ __forceinline__ unsigned int pack_bf16(float x, float y) {
    return ((unsigned int)f32_to_bf16_rne(y) << 16) | (unsigned int)f32_to_bf16_rne(x);
}

// ---------------- dtype detection ----------------
__global__ void detect_flags_kernel(const unsigned int* __restrict__ ew, int enwords,
                                    const unsigned short* __restrict__ xh, int xnh,
                                    int* __restrict__ flagI, int* __restrict__ flagD) {
    __shared__ int eodd_nz;
    __shared__ int xbig;
    if (threadIdx.x == 0) { eodd_nz = 0; xbig = 0; }
    __syncthreads();
    int f1 = 0;
    for (int i = 1 + 2 * (int)threadIdx.x; i < enwords; i += 2 * (int)blockDim.x)
        if (ew[i] != 0u) f1 = 1;
    int c = 0;
    for (int i = 2 * (int)threadIdx.x; i < xnh; i += 2 * (int)blockDim.x) {
        unsigned int e = ((unsigned int)xh[i] >> 7) & 0xFFu;
        if (e >= 0xC0u) c++;   // |v| >= 2^65 viewed as bf16 -> impossible for real data
    }
    if (f1) eodd_nz = 1;
    if (c) atomicAdd(&xbig, c);
    __syncthreads();
    if (threadIdx.x == 0) {
        *flagI = (eodd_nz == 0) ? 1 : 0;
        *flagD = (xbig > 8) ? 0 : 1;
    }
}

// ---------------- PREP: count_rank + cast_x + cast_wb fused (block-range dispatch) ----
// count_rank (g1 blocks): atomic-latency-bound, low BW. cast_x (g2 blocks): pure
// streaming, BW-bound. Independent work -> merged so the atomic round-trips hide
// under the cast's streaming, and 2 kernel launches are saved.
__global__ __launch_bounds__(256) void prep_kernel(
        const int* __restrict__ eidx, const int* __restrict__ flagI,
        const int* __restrict__ flagD, int E, int n,
        int* __restrict__ cnt, int* __restrict__ rank,
        const void* __restrict__ x, uint2* __restrict__ xb, int nw2,
        const void* __restrict__ W, const void* __restrict__ b,
        unsigned short* __restrict__ Wb, float* __restrict__ bias_f,
        int g1, int g2) {
    int bid = (int)blockIdx.x;
    if (bid < g1) {
        // ---- count_rank: degree count + per-edge slot rank (ONE atomic pass) ----
        int t = bid * 256 + (int)threadIdx.x;
        int base = t * 4;
        if (base >= E) return;
        int isI64 = *flagI;
        const long long* p64 = (const long long*)eidx;
        int s[4], d[4];
#pragma unroll
        for (int j = 0; j < 4; ++j) {
            int e = base + j;
            if (e < E) {
                if (isI64) { s[j] = (int)p64[e]; d[j] = (int)p64[(long long)E + e]; }
                else       { s[j] = eidx[e];     d[j] = eidx[E + e]; }
            } else { s[j] = -1; d[j] = -1; }
        }
        int r[4];
#pragma unroll
        for (int j = 0; j < 4; ++j) {
            bool ok = ((unsigned)d[j] < (unsigned)n) && ((unsigned)s[j] < (unsigned)n);
            r[j] = ok ? atomicAdd(&cnt[d[j]], 1) : 0;
        }
        if (base + 3 < E) {
            *(int4*)&rank[base] = make_int4(r[0], r[1], r[2], r[3]);
        } else {
#pragma unroll
            for (int j = 0; j < 4; ++j)
                if (base + j < E) rank[base + j] = r[j];
        }
    } else if (bid < g1 + g2) {
        // ---- cast_x: x -> packed bf16 rows (or copy if already bf16) ----
        int i = (bid - g1) * 256 + (int)threadIdx.x;
        if (i >= nw2) return;
        if (*flagD) {
            xb[i] = ((const uint2*)x)[i];
        } else {
            float4 v = ((const float4*)x)[i];
            uint2 o;
            o.x = pack_bf16(v.x, v.y);
            o.y = pack_bf16(v.z, v.w);
            xb[i] = o;
        }
    } else {
        // ---- cast_wb: W -> bf16, b -> fp32 ----
        int i = (bid - g1 - g2) * 256 + (int)threadIdx.x;
        int bf = *flagD;
        if (i < 128 * 128)
            Wb[i] = bf ? ((const unsigned short*)W)[i] : f32_to_bf16_rne(((const float*)W)[i]);
        if (i < 128)
            bias_f[i] = bf ? bf16_lo((unsigned int)((const unsigned short*)b)[i]) : ((const float*)b)[i];
    }
}

// ---------------- exclusive scan of cnt -> row_start ----------------
__global__ void scan_blocks_kernel(const int* __restrict__ cnt, int* __restrict__ row_start,
                                   int* __restrict__ partials, int n) {
    __shared__ int s[256];
    int i = blockIdx.x * 256 + threadIdx.x;
    int v = (i < n) ? cnt[i] : 0;
    s[threadIdx.x] = v;
    __syncthreads();
    for (int off = 1; off < 256; off <<= 1) {
        int t = ((int)threadIdx.x >= off) ? s[threadIdx.x - off] : 0;
        __syncthreads();
        s[threadIdx.x] += t;
        __syncthreads();
    }
    if (i < n) row_start[i] = s[threadIdx.x] - v;
    if (threadIdx.x == 255) partials[blockIdx.x] = s[255];
}

__global__ void scan_partials_kernel(int* __restrict__ partials, int nparts) {
    __shared__ int s[512];
    int v = ((int)threadIdx.x < nparts) ? partials[threadIdx.x] : 0;
    s[threadIdx.x] = v;
    __syncthreads();
    for (int off = 1; off < 512; off <<= 1) {
        int t = ((int)threadIdx.x >= off) ? s[threadIdx.x - off] : 0;
        __syncthreads();
        s[threadIdx.x] += t;
        __syncthreads();
    }
    if ((int)threadIdx.x < nparts) partials[threadIdx.x] = s[threadIdx.x] - v;
}

// finalize rows + fused dinv (one fewer dispatch)
__global__ void finalize_rows_kernel(int* __restrict__ row_start, const int* __restrict__ partials,
                                     const int* __restrict__ cnt, float* __restrict__ dinv, int n) {
    int i = blockIdx.x * 256 + threadIdx.x;
    if (i < n) {
        int r = row_start[i] + partials[blockIdx.x];
        row_start[i] = r;
        dinv[i] = rsqrtf((float)(cnt[i] + 1));
        if (i == n - 1) row_start[n] = r + cnt[i];
    }
}

// ---------------- pass 2: ATOMIC-FREE CSR scatter ----------------
__global__ __launch_bounds__(256) void scatter_kernel(const int* __restrict__ eidx,
                                                      const int* __restrict__ flagI,
                                                      const int* __restrict__ rank,
                                                      const int* __restrict__ row_start,
                                                      int E, int n, const float* __restrict__ dinv,
                                                      int2* __restrict__ csr) {
    int t = blockIdx.x * blockDim.x + threadIdx.x;
    int base = t * 4;
    if (base >= E) return;
    int isI64 = *flagI;
    const long long* p64 = (const long long*)eidx;
    int s[4], d[4], r[4];
    if (base + 3 < E) {
        int4 rv = *(const int4*)&rank[base];
        r[0] = rv.x; r[1] = rv.y; r[2] = rv.z; r[3] = rv.w;
#pragma unroll
        for (int j = 0; j < 4; ++j) {
            int e = base + j;
            if (isI64) { s[j] = (int)p64[e]; d[j] = (int)p64[(long long)E + e]; }
            else       { s[j] = eidx[e];     d[j] = eidx[E + e]; }
        }
    } else {
#pragma unroll
        for (int j = 0; j < 4; ++j) {
            int e = base + j;
            if (e < E) {
                r[j] = rank[e];
                if (isI64) { s[j] = (int)p64[e]; d[j] = (int)p64[(long long)E + e]; }
                else       { s[j] = eidx[e];     d[j] = eidx[E + e]; }
            } else { s[j] = -1; d[j] = -1; r[j] = 0; }
        }
    }
#pragma unroll
    for (int j = 0; j < 4; ++j) {
        bool ok = ((unsigned)d[j] < (unsigned)n) && ((unsigned)s[j] < (unsigned)n);
        if (ok) {
            int pos = row_start[d[j]] + r[j];
            int2 pk;
            pk.x = s[j];
            pk.y = __float_as_int(dinv[s[j]]);
            csr[pos] = pk;
        }
    }
}

// ---------------- hop: one wave per node, quarter-wave uint4 gathers, 2x-MLP ----------------
// lane = 16*e + c (e: edge slot 0..3, c: 16B chunk 0..15). 2x-unrolled loop: two
// independent csr loads + two independent 256B row gathers per iteration (8 gathers
// in flight per wave). Round-7 evidence: 43.2us, 3.1 TB/s on L2-miss path, VALUBusy
// 52% — near the random-gather throughput ceiling; kept identical this round.
// out[i] = di*(di*self + sum_s dinv[s]*h[s])
__global__ __launch_bounds__(256) void hop_kernel(const uint4* __restrict__ hin,
                                                  uint4* __restrict__ hout,
                                                  const int2* __restrict__ csr,
                                                  const int* __restrict__ row_start,
                                                  const float* __restrict__ dinv, int n) {
    int gw = (int)((blockIdx.x * 256 + threadIdx.x) >> 6);
    int lane = (int)(threadIdx.x & 63);
    if (gw >= n) return;
    int e = lane >> 4, c = lane & 15;
    float di = dinv[gw];
    int beg = row_start[gw], end = row_start[gw + 1];
    uint4 sv = hin[(size_t)gw * 16 + c];     // self row (broadcast across quarters)
    float a0 = 0.f, a1 = 0.f, a2 = 0.f, a3 = 0.f, a4 = 0.f, a5 = 0.f, a6 = 0.f, a7 = 0.f;
    for (int j = beg + e; j < end; j += 8) {
        int2 ed0 = csr[j];
        bool has1 = (j + 4) < end;
        int2 ed1 = has1 ? csr[j + 4] : ed0;
        uint4 v0 = hin[(size_t)ed0.x * 16 + c];          // two independent gathers
        uint4 v1 = hin[(size_t)ed1.x * 16 + c];          // in flight concurrently
        float w0 = __int_as_float(ed0.y);
        float w1 = has1 ? __int_as_float(ed1.y) : 0.f;
        a0 += w0 * bf16_lo(v0.x); a1 += w0 * bf16_hi(v0.x);
        a2 += w0 * bf16_lo(v0.y); a3 += w0 * bf16_hi(v0.y);
        a4 += w0 * bf16_lo(v0.z); a5 += w0 * bf16_hi(v0.z);
        a6 += w0 * bf16_lo(v0.w); a7 += w0 * bf16_hi(v0.w);
        a0 += w1 * bf16_lo(v1.x); a1 += w1 * bf16_hi(v1.x);
        a2 += w1 * bf16_lo(v1.y); a3 += w1 * bf16_hi(v1.y);
        a4 += w1 * bf16_lo(v1.z); a5 += w1 * bf16_hi(v1.z);
        a6 += w1 * bf16_lo(v1.w); a7 += w1 * bf16_hi(v1.w);
    }
    // reduce the 4 quarter-partials for each column set
    a0 += __shfl_xor(a0, 16); a0 += __shfl_xor(a0, 32);
    a1 += __shfl_xor(a1, 16); a1 += __shfl_xor(a1, 32);
    a2 += __shfl_xor(a2, 16); a2 += __shfl_xor(a2, 32);
    a3 += __shfl_xor(a3, 16); a3 += __shfl_xor(a3, 32);
    a4 += __shfl_xor(a4, 16); a4 += __shfl_xor(a4, 32);
    a5 += __shfl_xor(a5, 16); a5 += __shfl_xor(a5, 32);
    a6 += __shfl_xor(a6, 16); a6 += __shfl_xor(a6, 32);
    a7 += __shfl_xor(a7, 16); a7 += __shfl_xor(a7, 32);
    // add self term and final scale
    a0 = di * (a0 + di * bf16_lo(sv.x)); a1 = di * (a1 + di * bf16_hi(sv.x));
    a2 = di * (a2 + di * bf16_lo(sv.y)); a3 = di * (a3 + di * bf16_hi(sv.y));
    a4 = di * (a4 + di * bf16_lo(sv.z)); a5 = di * (a5 + di * bf16_hi(sv.z));
    a6 = di * (a6 + di * bf16_lo(sv.w)); a7 = di * (a7 + di * bf16_hi(sv.w));
    if (e == 0) {
        uint4 o;
        o.x = pack_bf16(a0, a1);
        o.y = pack_bf16(a2, a3);
        o.z = pack_bf16(a4, a5);
        o.w = pack_bf16(a6, a7);
        hout[(size_t)gw * 16 + c] = o;
    }
}

// ---------------- MFMA linear: out = h @ Wb^T + bias (h,Wb bf16; out per flagD) ----------------
__global__ __launch_bounds__(256, 2) void linear_mfma_kernel(
        const unsigned short* __restrict__ h, const unsigned short* __restrict__ Wb,
        const float* __restrict__ bias_f, void* __restrict__ out,
        const int* __restrict__ flagD, int n) {
    int bf = *flagD;
    int wave = (int)(threadIdx.x >> 6);
    int lane = (int)(threadIdx.x & 63);
    int q = lane >> 4, m16 = lane & 15;

    shortx8 bfrag[8][4];
    float bias[8];
#pragma unroll
    for (int nt = 0; nt < 8; ++nt) {
        int wr = nt * 16 + m16;               // W row = output feature o
#pragma unroll
        for (int t = 0; t < 4; ++t)
            bfrag[nt][t] = *(const shortx8*)&Wb[wr * 128 + t * 32 + q * 8];
        bias[nt] = bias_f[wr];
    }

    int nstrips = (n + 15) / 16;
    int wid = (int)blockIdx.x * 4 + wave;
    int nw = (int)gridDim.x * 4;
    for (int s = wid; s < nstrips; s += nw) {
        int row0 = s * 16;
        int arow = row0 + m16;
        if (arow >= n) arow = n - 1;          // clamp (dup rows; stores guarded)
        shortx8 afrag[4];
#pragma unroll
        for (int t = 0; t < 4; ++t)
            afrag[t] = *(const shortx8*)&h[(size_t)arow * 128 + t * 32 + q * 8];

        floatx4 acc[8];
#pragma unroll
        for (int nt = 0; nt < 8; ++nt) acc[nt] = (floatx4){0.f, 0.f, 0.f, 0.f};
#pragma unroll
        for (int t = 0; t < 4; ++t)
#pragma unroll
            for (int nt = 0; nt < 8; ++nt)
                acc[nt] = __builtin_amdgcn_mfma_f32_16x16x32_bf16(afrag[t], bfrag[nt][t], acc[nt], 0, 0, 0);

#pragma unroll
        for (int nt = 0; nt < 8; ++nt)
#pragma unroll
            for (int r = 0; r < 4; ++r) {
                int row = row0 + q * 4 + r;
                if (row < n) {
                    float v = acc[nt][r] + bias[nt];
                    size_t oi = (size_t)row * 128 + nt * 16 + m16;
                    if (bf) ((unsigned short*)out)[oi] = f32_to_bf16_rne(v);
                    else    ((float*)out)[oi] = v;
                }
            }
    }
}

extern "C" void kernel_launch(void* const* d_in, const int* in_sizes, int n_in,
                              void* d_out, int out_size, void* d_ws, size_t ws_size,
                              hipStream_t stream) {
    const void* x = d_in[0];
    const int* eidx = (const int*)d_in[1];
    const void* W = d_in[2];
    const void* b = d_in[3];

    int n = in_sizes[0] / DF;   // 100000
    int E = in_sizes[1] / 2;    // 800000

    // workspace carve-up (~37 MB; d_out hosts the second bf16 ping buffer,
    // safe because out_size*2B >= 25.6MB even for bf16 output)
    char* ws = (char*)d_ws;
    size_t off = 0;
    auto alloc = [&](size_t bytes) -> void* {
        void* p = ws + off;
        off = (off + bytes + 255) & ~(size_t)255;
        return p;
    };
    unsigned int* hb = (unsigned int*)alloc((size_t)n * 64 * 4);   // bf16 rows, 25.6MB
    float* dinv      = (float*)alloc((size_t)n * 4);
    int*   cnt       = (int*)alloc((size_t)n * 4);
    int*   row_start = (int*)alloc((size_t)(n + 1) * 4);
    int*   partials  = (int*)alloc(4096);
    int*   flagI     = (int*)alloc(256);
    int*   flagD     = (int*)alloc(256);
    unsigned short* Wb = (unsigned short*)alloc(128 * 128 * 2);    // bf16 W
    float* bias_f    = (float*)alloc(128 * 4);
    int2*  csr       = (int2*)alloc((size_t)E * 8);                // {src, dinv[src]}
    int*   rank      = (int*)alloc((size_t)E * 4);                 // per-edge slot rank
    unsigned int* xb = (unsigned int*)d_out;                       // bf16 ping buffer in d_out

    hipMemsetAsync(cnt, 0, (size_t)n * 4, stream);

    int enw = 8192; if (2 * E < enw) enw = 2 * E;
    int xnh = 16384; if (n * DF < xnh) xnh = n * DF;
    detect_flags_kernel<<<1, 256, 0, stream>>>((const unsigned int*)eidx, enw,
                                               (const unsigned short*)x, xnh, flagI, flagD);

    int nb = (n + 255) / 256;   // must be <= 512 for scan_partials
    int e4 = (E + 3) / 4;                       // threads (4 edges each)
    int g1 = (e4 + 255) / 256;                  // count_rank blocks
    int nw2 = n * 32;                           // uint2 count for cast_x
    int g2 = (nw2 + 255) / 256;                 // cast_x blocks
    int g3 = 64;                                // cast_wb blocks

    // fused prep: count_rank (atomic-latency) overlapped with cast_x/cast_wb (streaming)
    prep_kernel<<<g1 + g2 + g3, 256, 0, stream>>>(
        eidx, flagI, flagD, E, n, cnt, rank, x, (uint2*)xb, nw2,
        W, b, Wb, bias_f, g1, g2);

    scan_blocks_kernel<<<nb, 256, 0, stream>>>(cnt, row_start, partials, n);
    scan_partials_kernel<<<1, 512, 0, stream>>>(partials, nb);
    finalize_rows_kernel<<<nb, 256, 0, stream>>>(row_start, partials, cnt, dinv, n);
    scatter_kernel<<<g1, 256, 0, stream>>>(eidx, flagI, rank, row_start, E, n, dinv, csr);

    // hops ping-pong: xb(d_out) -> hb(ws) -> xb -> hb
    int hb_grid = (n + 3) / 4;
    hop_kernel<<<hb_grid, 256, 0, stream>>>((const uint4*)xb, (uint4*)hb, csr, row_start, dinv, n);
    hop_kernel<<<hb_grid, 256, 0, stream>>>((const uint4*)hb, (uint4*)xb, csr, row_start, dinv, n);
    hop_kernel<<<hb_grid, 256, 0, stream>>>((const uint4*)xb, (uint4*)hb, csr, row_start, dinv, n);

    // linear: reads hb (ws), writes full d_out (xb region is dead)
    int nstrips = (n + 15) / 16;
    int lgrid = 512; if ((nstrips + 3) / 4 < lgrid) lgrid = (nstrips + 3) / 4;
    linear_mfma_kernel<<<lgrid, 256, 0, stream>>>(
        (const unsigned short*)hb, Wb, bias_f, d_out, flagD, n);
}